// Round 13
// baseline (193.387 us; speedup 1.0000x reference)
//
#include <hip/hip_runtime.h>
#include <stdint.h>

// GraphConvLayer: 3x { x = X@W^T + b; x = Ahat @ x; x *= mask; x = gelu(x) }
// B=32, N=1024, D=256.
// R13: k_agg BARRIER-FREE. Same 128x128 geometry/bytes as R12, but each wave
//      is an independent pipeline: Y staged per-wave into a private 3-slot
//      4KB LDS ring via global_load_lds (no cross-wave sharing -> no
//      s_barrier at all); A fragments direct-to-register, 2-deep static sets.
//      Sync = per-wave counted vmcnt(12) (tails 8/0), sched_barrier pins.
//      8 async pipelines/CU vs R12's 2 barrier domains.
// Tiled layouts (bf16, 16B-aligned):
//   An : [b][mb=node/128][kt=k/32][row 128][32]   tile stride 4096 elems
//   Yt : [b][kt=node/32][feat 256][32]            tile stride 8192 elems

typedef __attribute__((ext_vector_type(8))) short short8;   // 8 bf16 (4 VGPRs)
typedef __attribute__((ext_vector_type(4))) float f32x4;    // MFMA acc

__device__ __forceinline__ uint16_t f2bf(float f) {
  uint32_t u = __float_as_uint(f);
  u += 0x7FFF + ((u >> 16) & 1);          // RNE
  return (uint16_t)(u >> 16);
}
__device__ __forceinline__ float bf2f(uint16_t h) {
  return __uint_as_float(((uint32_t)h) << 16);
}
__device__ __forceinline__ float gelu_exact(float v) {
  return 0.5f * v * (1.0f + erff(v * 0.70710678118654752f));
}
__device__ __forceinline__ f32x4 mfma16(short8 a, short8 b, f32x4 c) {
  return __builtin_amdgcn_mfma_f32_16x16x32_bf16(a, b, c, 0, 0, 0);
}

#define GLD16(gsrc, ldst) __builtin_amdgcn_global_load_lds(                    \
    (const __attribute__((address_space(1))) void*)(gsrc),                     \
    (__attribute__((address_space(3))) void*)(ldst), 16, 0, 0)

// ---------------- cast f32 -> bf16 (hi only) ----------------
__global__ void k_cast(const float* __restrict__ src, uint16_t* __restrict__ h,
                       int n4) {
  int i = blockIdx.x * blockDim.x + threadIdx.x;
  if (i >= n4) return;
  const float4 v = ((const float4*)src)[i];
  float vv[4] = {v.x, v.y, v.z, v.w};
  ushort4 hh;
  uint16_t* hp = (uint16_t*)&hh;
#pragma unroll
  for (int e = 0; e < 4; ++e) hp[e] = f2bf(vv[e]);
  ((ushort4*)h)[i] = hh;
}

// ---------------- split 3 weight matrices f32 -> bf16 hi/lo (one launch) ----
__global__ void k_split3(const float* __restrict__ s0, const float* __restrict__ s1,
                         const float* __restrict__ s2,
                         uint16_t* __restrict__ h, uint16_t* __restrict__ l) {
  const int blk = blockIdx.x >> 6;                 // 0..2 -> which W
  const int i = (blockIdx.x & 63) * 256 + threadIdx.x;   // 0..16383 (float4 idx)
  const float* src = (blk == 0) ? s0 : (blk == 1) ? s1 : s2;
  const float4 v = ((const float4*)src)[i];
  float vv[4] = {v.x, v.y, v.z, v.w};
  ushort4 hh, ll;
  uint16_t* hp = (uint16_t*)&hh;
  uint16_t* lp = (uint16_t*)&ll;
#pragma unroll
  for (int e = 0; e < 4; ++e) {
    uint16_t hb = f2bf(vv[e]);
    hp[e] = hb;
    lp[e] = f2bf(vv[e] - bf2f(hb));
  }
  ((ushort4*)(h + blk * 65536))[i] = hh;
  ((ushort4*)(l + blk * 65536))[i] = ll;
}

// ---------------- row-normalize adj -> bf16, TILED store ----------------
__global__ void k_norm_adj(const float* __restrict__ adj, uint16_t* __restrict__ An) {
  const int r = blockIdx.x;       // 0..32767 = b*1024 + node
  const int t = threadIdx.x;      // 0..255, handles k = t*4 .. t*4+3
  const float* row = adj + (size_t)r * 1024;
  const float4 v = *(const float4*)(row + t * 4);
  float s = v.x + v.y + v.z + v.w;
#pragma unroll
  for (int off = 32; off; off >>= 1) s += __shfl_down(s, off);
  __shared__ float ws[4];
  if ((t & 63) == 0) ws[t >> 6] = s;
  __syncthreads();
  const float deg = ws[0] + ws[1] + ws[2] + ws[3];
  const float dinv = (deg != 0.f) ? 1.f / deg : 0.f;
  ushort4 o;
  uint16_t* op = (uint16_t*)&o;
  float vv[4] = {v.x, v.y, v.z, v.w};
#pragma unroll
  for (int e = 0; e < 4; ++e) op[e] = f2bf(vv[e] * dinv);
  // tiled: [b][mb][kt][row 128][32]
  const int b = r >> 10, node = r & 1023;
  const int mb = node >> 7, rr = node & 127;
  const int kt = t >> 3, ko = (t * 4) & 31;
  const size_t oo = (size_t)(b * 8 + mb) * 131072 + kt * 4096 + rr * 32 + ko;
  *(ushort4*)(An + oo) = o;
}

// ---------------- linear: Yt = (Xh @ W^T + b), 2-term, TILED store ----------------
__global__ __launch_bounds__(256) void k_linear(
    const uint16_t* __restrict__ Xh,
    const uint16_t* __restrict__ Wh, const uint16_t* __restrict__ Wl,
    const float* __restrict__ bias,
    uint16_t* __restrict__ Yth) {
  __shared__ __align__(16) uint8_t smem[24576];  // Xh|Wh|Wl tiles, 8KB each
  const int tid = threadIdx.x;
  const int lane = tid & 63;
  const int wave = tid >> 6;
  const int wr = wave >> 1, wc = wave & 1;
  const int m0 = blockIdx.x * 128;   // global row (b*1024+node)
  const int n0 = blockIdx.y * 128;   // out-feature
  const int lm = lane & 15, g = lane >> 4;
  const int srow = lane >> 2;
  const int skof = (lane & 3) * 8;

  f32x4 acc[4][4] = {};

  for (int kt = 0; kt < 8; ++kt) {
    const int k0 = kt * 32;
    __syncthreads();
#pragma unroll
    for (int j = 0; j < 6; ++j) {
      const int c = j * 4 + wave;    // 0..23
      const int sub = c & 7, which = c >> 3;
      const int row = sub * 16 + srow;
      const uint16_t* src;
      if (which == 0)      src = Xh + (size_t)(m0 + row) * 256 + k0 + skof;
      else if (which == 1) src = Wh + (size_t)(n0 + row) * 256 + k0 + skof;
      else                 src = Wl + (size_t)(n0 + row) * 256 + k0 + skof;
      GLD16(src, smem + c * 1024);
    }
    asm volatile("s_waitcnt vmcnt(0)" ::: "memory");
    __syncthreads();

    const uint8_t* Ahs = smem;
    const uint8_t* Bhs = smem + 8192;
    const uint8_t* Bls = smem + 16384;
    short8 ah[4], bh[4], bl[4];
#pragma unroll
    for (int f = 0; f < 4; ++f) {
      ah[f] = *(const short8*)(Ahs + (wr * 64 + f * 16 + lm) * 64 + g * 16);
      bh[f] = *(const short8*)(Bhs + (wc * 64 + f * 16 + lm) * 64 + g * 16);
      bl[f] = *(const short8*)(Bls + (wc * 64 + f * 16 + lm) * 64 + g * 16);
    }
#pragma unroll
    for (int fm = 0; fm < 4; ++fm)
#pragma unroll
      for (int fn = 0; fn < 4; ++fn) {
        acc[fm][fn] = mfma16(ah[fm], bh[fn], acc[fm][fn]);
        acc[fm][fn] = mfma16(ah[fm], bl[fn], acc[fm][fn]);
      }
  }

  // epilogue: +bias, store hi-only TILED [b][kt][feat][32]
#pragma unroll
  for (int fn = 0; fn < 4; ++fn) {
    const int n = n0 + wc * 64 + fn * 16 + lm;
    const float bv = bias[n];
#pragma unroll
    for (int fm = 0; fm < 4; ++fm) {
      const int mg = m0 + wr * 64 + fm * 16 + g * 4;
      const int bb = mg >> 10, node = mg & 1023;
      const int kt = node >> 5, ko = node & 31;
      ushort4 hh;
      uint16_t* hp = (uint16_t*)&hh;
#pragma unroll
      for (int e = 0; e < 4; ++e) hp[e] = f2bf(acc[fm][fn][e] + bv);
      const size_t o = ((size_t)(bb * 32 + kt) * 256 + n) * 32 + ko;
      *(ushort4*)(Yth + o) = hh;
    }
  }
}

// ---------------- aggregate: Z = An[b] @ Yh, mask, gelu — BARRIER-FREE ------
// BM=128, BN=128, BK=32. Grid 512 (2 blocks/CU). 4 waves (2M x 2N), wave
// tile 64x64 (acc[4][4]). Per-wave private 3-slot x 4KB LDS ring for Y
// (GLD-staged); A direct-to-reg 2-deep (afA/afB). No s_barrier anywhere;
// per-wave counted vmcnt(12) / tail 8 / 0.
// Per step t: [issue Y-GLD(t+2) x4] [vmcnt(12)] [16 MFMA] [load A(t+2) x4].
#define ASTEP(AF) {                                                            \
    _Pragma("unroll")                                                          \
    for (int j = 0; j < 4; ++j)                                                \
      GLD16(yBase + (size_t)ks * 8192 + j * 512 + lane * 8,                    \
            myl + ssl + j * 1024);                                             \
    __builtin_amdgcn_sched_barrier(0);                                         \
    asm volatile("s_waitcnt vmcnt(12)" ::: "memory");                          \
    __builtin_amdgcn_sched_barrier(0);                                         \
    {                                                                          \
      const uint8_t* sb = myl + csl;                                           \
      __builtin_amdgcn_s_setprio(1);                                           \
      _Pragma("unroll")                                                        \
      for (int fn = 0; fn < 4; ++fn) {                                         \
        const short8 hf = *(const short8*)(sb + hoff + fn * 1024);             \
        _Pragma("unroll")                                                      \
        for (int fm = 0; fm < 4; ++fm)                                         \
          acc[fm][fn] = mfma16(AF[fm], hf, acc[fm][fn]);                       \
      }                                                                        \
      __builtin_amdgcn_s_setprio(0);                                           \
    }                                                                          \
    __builtin_amdgcn_sched_barrier(0);                                         \
    _Pragma("unroll")                                                          \
    for (int f = 0; f < 4; ++f)                                                \
      AF[f] = *(const short8*)(aBase + (size_t)ks * 4096 + f * 512);           \
    ks++;                                                                      \
    csl += 4096; if (csl == 12288) csl = 0;                                    \
    ssl += 4096; if (ssl == 12288) ssl = 0;                                    \
  }

#define ATAIL(AF, VM) {                                                        \
    asm volatile("s_waitcnt vmcnt(" #VM ")" ::: "memory");                     \
    __builtin_amdgcn_sched_barrier(0);                                         \
    const uint8_t* sb = myl + csl;                                             \
    __builtin_amdgcn_s_setprio(1);                                             \
    _Pragma("unroll")                                                          \
    for (int fn = 0; fn < 4; ++fn) {                                           \
      const short8 hf = *(const short8*)(sb + hoff + fn * 1024);               \
      _Pragma("unroll")                                                        \
      for (int fm = 0; fm < 4; ++fm)                                           \
        acc[fm][fn] = mfma16(AF[fm], hf, acc[fm][fn]);                         \
    }                                                                          \
    __builtin_amdgcn_s_setprio(0);                                             \
    csl += 4096; if (csl == 12288) csl = 0;                                    \
  }

template <bool LAST>
__global__ __launch_bounds__(256, 2) void k_agg(
    const uint16_t* __restrict__ An,
    const uint16_t* __restrict__ Yth,
    const float* __restrict__ mask,
    uint16_t* __restrict__ Xh,
    float* __restrict__ out) {
  __shared__ __align__(16) uint8_t smem[49152];   // 4 waves x 12KB private ring
  const int tid = threadIdx.x;
  const int lane = tid & 63;
  const int w = tid >> 6;               // 0..3
  const int wm = w >> 1, wn = w & 1;    // 2(M) x 2(N)
  const int id = blockIdx.x;            // 0..511
  const int swz = (id & 7) * 64 + (id >> 3);      // XCD-chunked (bijective)
  const int b = swz >> 4;               // batch
  const int rest = swz & 15;
  const int mb = rest >> 1;             // 128-row block
  const int nh = rest & 1;              // feature half
  const int lm = lane & 15, g = lane >> 4;

  uint8_t* myl = smem + w * 12288;      // wave-private ring base
  // A fragment source (per-lane): + kt*4096 + f*512
  const uint16_t* aBase = An + (size_t)(b * 8 + mb) * 131072
                             + (wm * 64 + lm) * 32 + g * 8;
  // Y staging source: wave's 64 feats, contiguous 4KB span per kt
  const uint16_t* yBase = Yth + (size_t)b * 262144 + (nh * 128 + wn * 64) * 32;
  const int hoff = lm * 64 + g * 16;    // + fn*1024 within slot

  f32x4 acc[4][4] = {};
  short8 afA[4], afB[4];

  // prologue — issue order pins oldest-8 = {Y(0), A(0)}: Y0, A0, Y1, A1
#pragma unroll
  for (int j = 0; j < 4; ++j)
    GLD16(yBase + j * 512 + lane * 8, myl + j * 1024);
  __builtin_amdgcn_sched_barrier(0);
#pragma unroll
  for (int f = 0; f < 4; ++f) afA[f] = *(const short8*)(aBase + f * 512);
  __builtin_amdgcn_sched_barrier(0);
#pragma unroll
  for (int j = 0; j < 4; ++j)
    GLD16(yBase + 8192 + j * 512 + lane * 8, myl + 4096 + j * 1024);
  __builtin_amdgcn_sched_barrier(0);
#pragma unroll
  for (int f = 0; f < 4; ++f) afB[f] = *(const short8*)(aBase + 4096 + f * 512);
  __builtin_amdgcn_sched_barrier(0);

  int ks = 2;                 // next tile to stage
  int csl = 0, ssl = 8192;    // compute-slot, stage-slot byte offsets
#pragma unroll 1
  for (int tp = 0; tp < 15; ++tp) {   // t = 0..29
    ASTEP(afA);
    ASTEP(afB);
  }
  ATAIL(afA, 8);              // t = 30
  ATAIL(afB, 0);              // t = 31

  // epilogue: mask (per out-node), exact gelu, store row-major (bf16 hi only)
  const float* mk_b = mask + b * 1024;
#pragma unroll
  for (int fm = 0; fm < 4; ++fm) {
    const int m = mb * 128 + wm * 64 + fm * 16 + g * 4;
    float mk[4];
#pragma unroll
    for (int e = 0; e < 4; ++e) mk[e] = mk_b[m + e];
#pragma unroll
    for (int fn = 0; fn < 4; ++fn) {
      const int n = nh * 128 + wn * 64 + fn * 16 + lm;
#pragma unroll
      for (int e = 0; e < 4; ++e) {
        const float v = gelu_exact(acc[fm][fn][e] * mk[e]);
        const size_t o = ((size_t)(b * 1024 + m + e)) * 256 + n;
        if (LAST) {
          out[o] = v;
        } else {
          Xh[o] = f2bf(v);
        }
      }
    }
  }
}

extern "C" void kernel_launch(void* const* d_in, const int* in_sizes, int n_in,
                              void* d_out, int out_size, void* d_ws, size_t ws_size,
                              hipStream_t stream) {
  const float* x    = (const float*)d_in[0];
  const float* mask = (const float*)d_in[1];
  const float* adj  = (const float*)d_in[2];
  const float* W[3]  = {(const float*)d_in[3], (const float*)d_in[5], (const float*)d_in[7]};
  const float* bs[3] = {(const float*)d_in[4], (const float*)d_in[6], (const float*)d_in[8]};

  uint8_t* ws = (uint8_t*)d_ws;
  uint16_t* An  = (uint16_t*)(ws);                    // 67108864 B (tiled)
  uint16_t* Xh  = (uint16_t*)(ws + 67108864);         // 16777216
  uint16_t* Yth = (uint16_t*)(ws + 83886080);         // 16777216 (tiled)
  uint16_t* Wh  = (uint16_t*)(ws + 100663296);        // 393216
  uint16_t* Wl  = (uint16_t*)(ws + 101056512);        // 393216

  k_cast<<<dim3(8192), 256, 0, stream>>>(x, Xh, 2097152);
  k_split3<<<dim3(192), 256, 0, stream>>>(W[0], W[1], W[2], Wh, Wl);
  k_norm_adj<<<dim3(32768), 256, 0, stream>>>(adj, An);

  for (int l = 0; l < 3; ++l) {
    k_linear<<<dim3(256, 2), 256, 0, stream>>>(Xh, Wh + l * 65536, Wl + l * 65536,
                                               bs[l], Yth);
    if (l < 2)
      k_agg<false><<<dim3(512), 256, 0, stream>>>(An, Yth, mask, Xh, nullptr);
    else
      k_agg<true><<<dim3(512), 256, 0, stream>>>(An, Yth, mask, nullptr,
                                                 (float*)d_out);
  }
}

// Round 15
// 184.980 us; speedup vs baseline: 1.0455x; 1.0455x over previous
//
#include <hip/hip_runtime.h>
#include <stdint.h>

// GraphConvLayer: 3x { x = X@W^T + b; x = Ahat @ x; x *= mask; x = gelu(x) }
// B=32, N=1024, D=256.
// R15 = safe composite: k_agg reverted to R12 (proven deterministic ring:
//      4-slot x 16KB, GLD-staged, counted vmcnt(8), 1 barrier/step) +
//      R14's k_linear BM=64 (4 blocks/CU, classic double-sync) +
//      k_cast / k_split3 prologue. R14's mixed A-reg/Y-GLD agg raced on
//      replay re-validation -> reverted, not patched.
// Tiled layouts (bf16, 16B-aligned):
//   An : [b][mb=node/128][kt=k/32][row 128][32]   tile stride 4096 elems
//   Yt : [b][kt=node/32][feat 256][32]            tile stride 8192 elems

typedef __attribute__((ext_vector_type(8))) short short8;   // 8 bf16 (4 VGPRs)
typedef __attribute__((ext_vector_type(4))) float f32x4;    // MFMA acc

__device__ __forceinline__ uint16_t f2bf(float f) {
  uint32_t u = __float_as_uint(f);
  u += 0x7FFF + ((u >> 16) & 1);          // RNE
  return (uint16_t)(u >> 16);
}
__device__ __forceinline__ float bf2f(uint16_t h) {
  return __uint_as_float(((uint32_t)h) << 16);
}
__device__ __forceinline__ float gelu_exact(float v) {
  return 0.5f * v * (1.0f + erff(v * 0.70710678118654752f));
}
__device__ __forceinline__ f32x4 mfma16(short8 a, short8 b, f32x4 c) {
  return __builtin_amdgcn_mfma_f32_16x16x32_bf16(a, b, c, 0, 0, 0);
}

#define GLD16(gsrc, ldst) __builtin_amdgcn_global_load_lds(                    \
    (const __attribute__((address_space(1))) void*)(gsrc),                     \
    (__attribute__((address_space(3))) void*)(ldst), 16, 0, 0)

// ---------------- cast f32 -> bf16 (hi only) ----------------
__global__ void k_cast(const float* __restrict__ src, uint16_t* __restrict__ h,
                       int n4) {
  int i = blockIdx.x * blockDim.x + threadIdx.x;
  if (i >= n4) return;
  const float4 v = ((const float4*)src)[i];
  float vv[4] = {v.x, v.y, v.z, v.w};
  ushort4 hh;
  uint16_t* hp = (uint16_t*)&hh;
#pragma unroll
  for (int e = 0; e < 4; ++e) hp[e] = f2bf(vv[e]);
  ((ushort4*)h)[i] = hh;
}

// ---------------- split 3 weight matrices f32 -> bf16 hi/lo (one launch) ----
__global__ void k_split3(const float* __restrict__ s0, const float* __restrict__ s1,
                         const float* __restrict__ s2,
                         uint16_t* __restrict__ h, uint16_t* __restrict__ l) {
  const int blk = blockIdx.x >> 6;                 // 0..2 -> which W
  const int i = (blockIdx.x & 63) * 256 + threadIdx.x;   // float4 idx
  const float* src = (blk == 0) ? s0 : (blk == 1) ? s1 : s2;
  const float4 v = ((const float4*)src)[i];
  float vv[4] = {v.x, v.y, v.z, v.w};
  ushort4 hh, ll;
  uint16_t* hp = (uint16_t*)&hh;
  uint16_t* lp = (uint16_t*)&ll;
#pragma unroll
  for (int e = 0; e < 4; ++e) {
    uint16_t hb = f2bf(vv[e]);
    hp[e] = hb;
    lp[e] = f2bf(vv[e] - bf2f(hb));
  }
  ((ushort4*)(h + blk * 65536))[i] = hh;
  ((ushort4*)(l + blk * 65536))[i] = ll;
}

// ---------------- row-normalize adj -> bf16, TILED store ----------------
__global__ void k_norm_adj(const float* __restrict__ adj, uint16_t* __restrict__ An) {
  const int r = blockIdx.x;       // 0..32767 = b*1024 + node
  const int t = threadIdx.x;      // 0..255, handles k = t*4 .. t*4+3
  const float* row = adj + (size_t)r * 1024;
  const float4 v = *(const float4*)(row + t * 4);
  float s = v.x + v.y + v.z + v.w;
#pragma unroll
  for (int off = 32; off; off >>= 1) s += __shfl_down(s, off);
  __shared__ float ws[4];
  if ((t & 63) == 0) ws[t >> 6] = s;
  __syncthreads();
  const float deg = ws[0] + ws[1] + ws[2] + ws[3];
  const float dinv = (deg != 0.f) ? 1.f / deg : 0.f;
  ushort4 o;
  uint16_t* op = (uint16_t*)&o;
  float vv[4] = {v.x, v.y, v.z, v.w};
#pragma unroll
  for (int e = 0; e < 4; ++e) op[e] = f2bf(vv[e] * dinv);
  // tiled: [b][mb][kt][row 128][32]
  const int b = r >> 10, node = r & 1023;
  const int mb = node >> 7, rr = node & 127;
  const int kt = t >> 3, ko = (t * 4) & 31;
  const size_t oo = (size_t)(b * 8 + mb) * 131072 + kt * 4096 + rr * 32 + ko;
  *(ushort4*)(An + oo) = o;
}

// ---------------- linear: Yt = (Xh @ W^T + b), 2-term, TILED store ----------
// BM=64, BN=128. Grid (512, 2) = 1024 blocks = 4 blocks/CU. 4 waves 2Mx2N,
// wave tile 32x64 (acc[2][4]). Per K-step: 20 chunks (Xh 4 | Wh 8 | Wl 8),
// 5 GLD/wave. LDS 20KB.
__global__ __launch_bounds__(256, 4) void k_linear(
    const uint16_t* __restrict__ Xh,
    const uint16_t* __restrict__ Wh, const uint16_t* __restrict__ Wl,
    const float* __restrict__ bias,
    uint16_t* __restrict__ Yth) {
  __shared__ __align__(16) uint8_t smem[20480];  // Xh 4K | Wh 8K | Wl 8K
  const int tid = threadIdx.x;
  const int lane = tid & 63;
  const int wave = tid >> 6;
  const int wr = wave >> 1, wc = wave & 1;
  const int m0 = blockIdx.x * 64;    // global row (b*1024+node)
  const int n0 = blockIdx.y * 128;   // out-feature
  const int lm = lane & 15, g = lane >> 4;
  const int srow = lane >> 2;
  const int skof = (lane & 3) * 8;

  f32x4 acc[2][4] = {};

  for (int kt = 0; kt < 8; ++kt) {
    const int k0 = kt * 32;
    __syncthreads();
#pragma unroll
    for (int j = 0; j < 5; ++j) {
      const int c = j * 4 + wave;    // 0..19
      const uint16_t* src;
      if (c < 4)       src = Xh + (size_t)(m0 + c * 16 + srow) * 256 + k0 + skof;
      else if (c < 12) src = Wh + (size_t)(n0 + (c - 4) * 16 + srow) * 256 + k0 + skof;
      else             src = Wl + (size_t)(n0 + (c - 12) * 16 + srow) * 256 + k0 + skof;
      GLD16(src, smem + c * 1024);
    }
    asm volatile("s_waitcnt vmcnt(0)" ::: "memory");
    __syncthreads();

    short8 ah[2], bh[4], bl[4];
#pragma unroll
    for (int f = 0; f < 2; ++f)
      ah[f] = *(const short8*)(smem + (wr * 32 + f * 16 + lm) * 64 + g * 16);
#pragma unroll
    for (int f = 0; f < 4; ++f) {
      bh[f] = *(const short8*)(smem + 4096  + (wc * 64 + f * 16 + lm) * 64 + g * 16);
      bl[f] = *(const short8*)(smem + 12288 + (wc * 64 + f * 16 + lm) * 64 + g * 16);
    }
#pragma unroll
    for (int fm = 0; fm < 2; ++fm)
#pragma unroll
      for (int fn = 0; fn < 4; ++fn) {
        acc[fm][fn] = mfma16(ah[fm], bh[fn], acc[fm][fn]);
        acc[fm][fn] = mfma16(ah[fm], bl[fn], acc[fm][fn]);
      }
  }

  // epilogue: +bias, store hi-only TILED [b][kt][feat][32]
#pragma unroll
  for (int fn = 0; fn < 4; ++fn) {
    const int n = n0 + wc * 64 + fn * 16 + lm;
    const float bv = bias[n];
#pragma unroll
    for (int fm = 0; fm < 2; ++fm) {
      const int mg = m0 + wr * 32 + fm * 16 + g * 4;
      const int bb = mg >> 10, node = mg & 1023;
      const int kt = node >> 5, ko = node & 31;
      ushort4 hh;
      uint16_t* hp = (uint16_t*)&hh;
#pragma unroll
      for (int e = 0; e < 4; ++e) hp[e] = f2bf(acc[fm][fn][e] + bv);
      const size_t o = ((size_t)(bb * 32 + kt) * 256 + n) * 32 + ko;
      *(ushort4*)(Yth + o) = hh;
    }
  }
}

// ---------------- aggregate: Z = An[b] @ Yh, mask, gelu  (R12, proven) ------
// BM=128, BN=128, BK=32. Grid 512 (2 blocks/CU). 4 waves (2M x 2N), wave
// tile 64x64 (acc[4][4]). 4-slot LDS ring (slot = A 8KB | Yh-half 8KB),
// depth-3 prefetch, counted vmcnt(8). 4 GLD/wave/step.
#define STAGE(T, SSL) {                                                        \
    _Pragma("unroll")                                                          \
    for (int j = 0; j < 4; ++j) {                                              \
      const int c = w * 4 + j;                                                 \
      const uint16_t* src = (c < 8)                                            \
          ? aStep + (size_t)(T) * 4096 + c * 512                               \
          : yStep + (size_t)(T) * 8192 + (c - 8) * 512;                        \
      GLD16(src, smem + (SSL) + c * 1024);                                     \
    }                                                                          \
  }

template <bool LAST>
__global__ __launch_bounds__(256, 2) void k_agg(
    const uint16_t* __restrict__ An,
    const uint16_t* __restrict__ Yth,
    const float* __restrict__ mask,
    uint16_t* __restrict__ Xh,
    float* __restrict__ out) {
  __shared__ __align__(16) uint8_t smem[65536];   // 4 x 16384 ring
  const int tid = threadIdx.x;
  const int lane = tid & 63;
  const int w = tid >> 6;               // 0..3
  const int wm = w >> 1, wn = w & 1;    // 2(M) x 2(N)
  const int id = blockIdx.x;            // 0..511
  const int swz = (id & 7) * 64 + (id >> 3);      // XCD-chunked (bijective)
  const int b = swz >> 4;               // batch
  const int rest = swz & 15;
  const int mb = rest >> 1;             // 128-row block
  const int nh = rest & 1;              // feature half
  const int lm = lane & 15, g = lane >> 4;

  // per-lane staging sources (tiled layouts are GLD-linear)
  const uint16_t* aStep = An + (size_t)(b * 8 + mb) * 131072 + lane * 8;
  const uint16_t* yStep = Yth + (size_t)b * 262144 + nh * 4096 + lane * 8;

  // fragment read offsets (byte, slot-local)
  const int aoff = (wm * 64 + lm) * 64 + g * 16;           // + fm*1024
  const int boff = 8192 + (wn * 64 + lm) * 64 + g * 16;    // + fn*1024

  f32x4 acc[4][4] = {};

  // prologue: stage tiles 0,1,2 into slots 0,1,2
  STAGE(0, 0);
  STAGE(1, 16384);
  STAGE(2, 32768);

  int csl = 0, ssl = 49152;   // compute-slot, stage-slot byte offsets
#pragma unroll 1
  for (int t = 0; t < 32; ++t) {
    if (t < 30)      { asm volatile("s_waitcnt vmcnt(8)" ::: "memory"); }
    else if (t == 30){ asm volatile("s_waitcnt vmcnt(4)" ::: "memory"); }
    else             { asm volatile("s_waitcnt vmcnt(0)" ::: "memory"); }
    __builtin_amdgcn_s_barrier();
    __builtin_amdgcn_sched_barrier(0);
    if (t < 29) { STAGE(t + 3, ssl); }
    __builtin_amdgcn_sched_barrier(0);

    const uint8_t* sb = smem + csl;
    short8 af[4];
#pragma unroll
    for (int f = 0; f < 4; ++f) af[f] = *(const short8*)(sb + aoff + f * 1024);
    __builtin_amdgcn_s_setprio(1);
#pragma unroll
    for (int fn = 0; fn < 4; ++fn) {
      const short8 hf = *(const short8*)(sb + boff + fn * 1024);
#pragma unroll
      for (int fm = 0; fm < 4; ++fm)
        acc[fm][fn] = mfma16(af[fm], hf, acc[fm][fn]);
    }
    __builtin_amdgcn_s_setprio(0);

    csl += 16384; if (csl == 65536) csl = 0;
    ssl += 16384; if (ssl == 65536) ssl = 0;
  }

  // epilogue: mask (per out-node), exact gelu, store row-major (bf16 hi only)
  const float* mk_b = mask + b * 1024;
#pragma unroll
  for (int fm = 0; fm < 4; ++fm) {
    const int m = mb * 128 + wm * 64 + fm * 16 + g * 4;
    float mk[4];
#pragma unroll
    for (int e = 0; e < 4; ++e) mk[e] = mk_b[m + e];
#pragma unroll
    for (int fn = 0; fn < 4; ++fn) {
      const int n = nh * 128 + wn * 64 + fn * 16 + lm;
#pragma unroll
      for (int e = 0; e < 4; ++e) {
        const float v = gelu_exact(acc[fm][fn][e] * mk[e]);
        const size_t o = ((size_t)(b * 1024 + m + e)) * 256 + n;
        if (LAST) {
          out[o] = v;
        } else {
          Xh[o] = f2bf(v);
        }
      }
    }
  }
}

extern "C" void kernel_launch(void* const* d_in, const int* in_sizes, int n_in,
                              void* d_out, int out_size, void* d_ws, size_t ws_size,
                              hipStream_t stream) {
  const float* x    = (const float*)d_in[0];
  const float* mask = (const float*)d_in[1];
  const float* adj  = (const float*)d_in[2];
  const float* W[3]  = {(const float*)d_in[3], (const float*)d_in[5], (const float*)d_in[7]};
  const float* bs[3] = {(const float*)d_in[4], (const float*)d_in[6], (const float*)d_in[8]};

  uint8_t* ws = (uint8_t*)d_ws;
  uint16_t* An  = (uint16_t*)(ws);                    // 67108864 B (tiled)
  uint16_t* Xh  = (uint16_t*)(ws + 67108864);         // 16777216
  uint16_t* Yth = (uint16_t*)(ws + 83886080);         // 16777216 (tiled)
  uint16_t* Wh  = (uint16_t*)(ws + 100663296);        // 393216
  uint16_t* Wl  = (uint16_t*)(ws + 101056512);        // 393216

  k_cast<<<dim3(8192), 256, 0, stream>>>(x, Xh, 2097152);
  k_split3<<<dim3(192), 256, 0, stream>>>(W[0], W[1], W[2], Wh, Wl);
  k_norm_adj<<<dim3(32768), 256, 0, stream>>>(adj, An);

  for (int l = 0; l < 3; ++l) {
    k_linear<<<dim3(512, 2), 256, 0, stream>>>(Xh, Wh + l * 65536, Wl + l * 65536,
                                               bs[l], Yth);
    if (l < 2)
      k_agg<false><<<dim3(512), 256, 0, stream>>>(An, Yth, mask, Xh, nullptr);
    else
      k_agg<true><<<dim3(512), 256, 0, stream>>>(An, Yth, mask, nullptr,
                                                 (float*)d_out);
  }
}

// Round 16
// 180.084 us; speedup vs baseline: 1.0739x; 1.0272x over previous
//
#include <hip/hip_runtime.h>
#include <stdint.h>

// GraphConvLayer: 3x { x = X@W^T + b; x = Ahat @ x; x *= mask; x = gelu(x) }
// B=32, N=1024, D=256.
// R16 = R15 + merged prologue (k_prep = norm_adj | cast | split3 in one
//       launch; all-independent work, uniform per block). k_agg/k_linear
//       unchanged (proven deterministic, best measured).
// Tiled layouts (bf16, 16B-aligned):
//   An : [b][mb=node/128][kt=k/32][row 128][32]   tile stride 4096 elems
//   Yt : [b][kt=node/32][feat 256][32]            tile stride 8192 elems

typedef __attribute__((ext_vector_type(8))) short short8;   // 8 bf16 (4 VGPRs)
typedef __attribute__((ext_vector_type(4))) float f32x4;    // MFMA acc

__device__ __forceinline__ uint16_t f2bf(float f) {
  uint32_t u = __float_as_uint(f);
  u += 0x7FFF + ((u >> 16) & 1);          // RNE
  return (uint16_t)(u >> 16);
}
__device__ __forceinline__ float bf2f(uint16_t h) {
  return __uint_as_float(((uint32_t)h) << 16);
}
__device__ __forceinline__ float gelu_exact(float v) {
  return 0.5f * v * (1.0f + erff(v * 0.70710678118654752f));
}
__device__ __forceinline__ f32x4 mfma16(short8 a, short8 b, f32x4 c) {
  return __builtin_amdgcn_mfma_f32_16x16x32_bf16(a, b, c, 0, 0, 0);
}

#define GLD16(gsrc, ldst) __builtin_amdgcn_global_load_lds(                    \
    (const __attribute__((address_space(1))) void*)(gsrc),                     \
    (__attribute__((address_space(3))) void*)(ldst), 16, 0, 0)

// ---------------- merged prologue: norm_adj | cast x | split3 W ------------
// grid 41152 x 256:
//   [0, 32768)        row-normalize adj -> An (tiled bf16)
//   [32768, 40960)    cast x f32 -> Xh bf16   (8192 blocks x 256 = 2097152 float4)
//   [40960, 41152)    split W0..2 f32 -> Wh/Wl hi/lo (192 blocks)
__global__ void k_prep(const float* __restrict__ adj, uint16_t* __restrict__ An,
                       const float* __restrict__ x, uint16_t* __restrict__ Xh,
                       const float* __restrict__ w0, const float* __restrict__ w1,
                       const float* __restrict__ w2,
                       uint16_t* __restrict__ Wh, uint16_t* __restrict__ Wl) {
  __shared__ float ws[4];
  const int bid = blockIdx.x;
  const int t = threadIdx.x;
  if (bid < 32768) {
    // ---- row-normalize adj ----
    const int r = bid;              // b*1024 + node
    const float* row = adj + (size_t)r * 1024;
    const float4 v = *(const float4*)(row + t * 4);
    float s = v.x + v.y + v.z + v.w;
#pragma unroll
    for (int off = 32; off; off >>= 1) s += __shfl_down(s, off);
    if ((t & 63) == 0) ws[t >> 6] = s;
    __syncthreads();
    const float deg = ws[0] + ws[1] + ws[2] + ws[3];
    const float dinv = (deg != 0.f) ? 1.f / deg : 0.f;
    ushort4 o;
    uint16_t* op = (uint16_t*)&o;
    float vv[4] = {v.x, v.y, v.z, v.w};
#pragma unroll
    for (int e = 0; e < 4; ++e) op[e] = f2bf(vv[e] * dinv);
    const int b = r >> 10, node = r & 1023;
    const int mb = node >> 7, rr = node & 127;
    const int kt = t >> 3, ko = (t * 4) & 31;
    const size_t oo = (size_t)(b * 8 + mb) * 131072 + kt * 4096 + rr * 32 + ko;
    *(ushort4*)(An + oo) = o;
  } else if (bid < 40960) {
    // ---- cast x -> bf16 ----
    const int i = (bid - 32768) * 256 + t;   // float4 index, exact cover
    const float4 v = ((const float4*)x)[i];
    float vv[4] = {v.x, v.y, v.z, v.w};
    ushort4 hh;
    uint16_t* hp = (uint16_t*)&hh;
#pragma unroll
    for (int e = 0; e < 4; ++e) hp[e] = f2bf(vv[e]);
    ((ushort4*)Xh)[i] = hh;
  } else {
    // ---- split weights hi/lo ----
    const int sb = bid - 40960;              // 0..191
    const int blk = sb >> 6;                 // which W
    const int i = (sb & 63) * 256 + t;       // float4 index
    const float* src = (blk == 0) ? w0 : (blk == 1) ? w1 : w2;
    const float4 v = ((const float4*)src)[i];
    float vv[4] = {v.x, v.y, v.z, v.w};
    ushort4 hh, ll;
    uint16_t* hp = (uint16_t*)&hh;
    uint16_t* lp = (uint16_t*)&ll;
#pragma unroll
    for (int e = 0; e < 4; ++e) {
      uint16_t hb = f2bf(vv[e]);
      hp[e] = hb;
      lp[e] = f2bf(vv[e] - bf2f(hb));
    }
    ((ushort4*)(Wh + blk * 65536))[i] = hh;
    ((ushort4*)(Wl + blk * 65536))[i] = ll;
  }
}

// ---------------- linear: Yt = (Xh @ W^T + b), 2-term, TILED store ----------
// BM=64, BN=128. Grid (512, 2) = 1024 blocks = 4 blocks/CU. 4 waves 2Mx2N,
// wave tile 32x64 (acc[2][4]). Per K-step: 20 chunks (Xh 4 | Wh 8 | Wl 8),
// 5 GLD/wave. LDS 20KB.
__global__ __launch_bounds__(256, 4) void k_linear(
    const uint16_t* __restrict__ Xh,
    const uint16_t* __restrict__ Wh, const uint16_t* __restrict__ Wl,
    const float* __restrict__ bias,
    uint16_t* __restrict__ Yth) {
  __shared__ __align__(16) uint8_t smem[20480];  // Xh 4K | Wh 8K | Wl 8K
  const int tid = threadIdx.x;
  const int lane = tid & 63;
  const int wave = tid >> 6;
  const int wr = wave >> 1, wc = wave & 1;
  const int m0 = blockIdx.x * 64;    // global row (b*1024+node)
  const int n0 = blockIdx.y * 128;   // out-feature
  const int lm = lane & 15, g = lane >> 4;
  const int srow = lane >> 2;
  const int skof = (lane & 3) * 8;

  f32x4 acc[2][4] = {};

  for (int kt = 0; kt < 8; ++kt) {
    const int k0 = kt * 32;
    __syncthreads();
#pragma unroll
    for (int j = 0; j < 5; ++j) {
      const int c = j * 4 + wave;    // 0..19
      const uint16_t* src;
      if (c < 4)       src = Xh + (size_t)(m0 + c * 16 + srow) * 256 + k0 + skof;
      else if (c < 12) src = Wh + (size_t)(n0 + (c - 4) * 16 + srow) * 256 + k0 + skof;
      else             src = Wl + (size_t)(n0 + (c - 12) * 16 + srow) * 256 + k0 + skof;
      GLD16(src, smem + c * 1024);
    }
    asm volatile("s_waitcnt vmcnt(0)" ::: "memory");
    __syncthreads();

    short8 ah[2], bh[4], bl[4];
#pragma unroll
    for (int f = 0; f < 2; ++f)
      ah[f] = *(const short8*)(smem + (wr * 32 + f * 16 + lm) * 64 + g * 16);
#pragma unroll
    for (int f = 0; f < 4; ++f) {
      bh[f] = *(const short8*)(smem + 4096  + (wc * 64 + f * 16 + lm) * 64 + g * 16);
      bl[f] = *(const short8*)(smem + 12288 + (wc * 64 + f * 16 + lm) * 64 + g * 16);
    }
#pragma unroll
    for (int fm = 0; fm < 2; ++fm)
#pragma unroll
      for (int fn = 0; fn < 4; ++fn) {
        acc[fm][fn] = mfma16(ah[fm], bh[fn], acc[fm][fn]);
        acc[fm][fn] = mfma16(ah[fm], bl[fn], acc[fm][fn]);
      }
  }

  // epilogue: +bias, store hi-only TILED [b][kt][feat][32]
#pragma unroll
  for (int fn = 0; fn < 4; ++fn) {
    const int n = n0 + wc * 64 + fn * 16 + lm;
    const float bv = bias[n];
#pragma unroll
    for (int fm = 0; fm < 2; ++fm) {
      const int mg = m0 + wr * 32 + fm * 16 + g * 4;
      const int bb = mg >> 10, node = mg & 1023;
      const int kt = node >> 5, ko = node & 31;
      ushort4 hh;
      uint16_t* hp = (uint16_t*)&hh;
#pragma unroll
      for (int e = 0; e < 4; ++e) hp[e] = f2bf(acc[fm][fn][e] + bv);
      const size_t o = ((size_t)(bb * 32 + kt) * 256 + n) * 32 + ko;
      *(ushort4*)(Yth + o) = hh;
    }
  }
}

// ---------------- aggregate: Z = An[b] @ Yh, mask, gelu  (R12, proven) ------
// BM=128, BN=128, BK=32. Grid 512 (2 blocks/CU). 4 waves (2M x 2N), wave
// tile 64x64 (acc[4][4]). 4-slot LDS ring (slot = A 8KB | Yh-half 8KB),
// depth-3 prefetch, counted vmcnt(8). 4 GLD/wave/step.
#define STAGE(T, SSL) {                                                        \
    _Pragma("unroll")                                                          \
    for (int j = 0; j < 4; ++j) {                                              \
      const int c = w * 4 + j;                                                 \
      const uint16_t* src = (c < 8)                                            \
          ? aStep + (size_t)(T) * 4096 + c * 512                               \
          : yStep + (size_t)(T) * 8192 + (c - 8) * 512;                        \
      GLD16(src, smem + (SSL) + c * 1024);                                     \
    }                                                                          \
  }

template <bool LAST>
__global__ __launch_bounds__(256, 2) void k_agg(
    const uint16_t* __restrict__ An,
    const uint16_t* __restrict__ Yth,
    const float* __restrict__ mask,
    uint16_t* __restrict__ Xh,
    float* __restrict__ out) {
  __shared__ __align__(16) uint8_t smem[65536];   // 4 x 16384 ring
  const int tid = threadIdx.x;
  const int lane = tid & 63;
  const int w = tid >> 6;               // 0..3
  const int wm = w >> 1, wn = w & 1;    // 2(M) x 2(N)
  const int id = blockIdx.x;            // 0..511
  const int swz = (id & 7) * 64 + (id >> 3);      // XCD-chunked (bijective)
  const int b = swz >> 4;               // batch
  const int rest = swz & 15;
  const int mb = rest >> 1;             // 128-row block
  const int nh = rest & 1;              // feature half
  const int lm = lane & 15, g = lane >> 4;

  // per-lane staging sources (tiled layouts are GLD-linear)
  const uint16_t* aStep = An + (size_t)(b * 8 + mb) * 131072 + lane * 8;
  const uint16_t* yStep = Yth + (size_t)b * 262144 + nh * 4096 + lane * 8;

  // fragment read offsets (byte, slot-local)
  const int aoff = (wm * 64 + lm) * 64 + g * 16;           // + fm*1024
  const int boff = 8192 + (wn * 64 + lm) * 64 + g * 16;    // + fn*1024

  f32x4 acc[4][4] = {};

  // prologue: stage tiles 0,1,2 into slots 0,1,2
  STAGE(0, 0);
  STAGE(1, 16384);
  STAGE(2, 32768);

  int csl = 0, ssl = 49152;   // compute-slot, stage-slot byte offsets
#pragma unroll 1
  for (int t = 0; t < 32; ++t) {
    if (t < 30)      { asm volatile("s_waitcnt vmcnt(8)" ::: "memory"); }
    else if (t == 30){ asm volatile("s_waitcnt vmcnt(4)" ::: "memory"); }
    else             { asm volatile("s_waitcnt vmcnt(0)" ::: "memory"); }
    __builtin_amdgcn_s_barrier();
    __builtin_amdgcn_sched_barrier(0);
    if (t < 29) { STAGE(t + 3, ssl); }
    __builtin_amdgcn_sched_barrier(0);

    const uint8_t* sb = smem + csl;
    short8 af[4];
#pragma unroll
    for (int f = 0; f < 4; ++f) af[f] = *(const short8*)(sb + aoff + f * 1024);
    __builtin_amdgcn_s_setprio(1);
#pragma unroll
    for (int fn = 0; fn < 4; ++fn) {
      const short8 hf = *(const short8*)(sb + boff + fn * 1024);
#pragma unroll
      for (int fm = 0; fm < 4; ++fm)
        acc[fm][fn] = mfma16(af[fm], hf, acc[fm][fn]);
    }
    __builtin_amdgcn_s_setprio(0);

    csl += 16384; if (csl == 65536) csl = 0;
    ssl += 16384; if (ssl == 65536) ssl = 0;
  }

  // epilogue: mask (per out-node), exact gelu, store row-major (bf16 hi only)
  const float* mk_b = mask + b * 1024;
#pragma unroll
  for (int fm = 0; fm < 4; ++fm) {
    const int m = mb * 128 + wm * 64 + fm * 16 + g * 4;
    float mk[4];
#pragma unroll
    for (int e = 0; e < 4; ++e) mk[e] = mk_b[m + e];
#pragma unroll
    for (int fn = 0; fn < 4; ++fn) {
      const int n = nh * 128 + wn * 64 + fn * 16 + lm;
#pragma unroll
      for (int e = 0; e < 4; ++e) {
        const float v = gelu_exact(acc[fm][fn][e] * mk[e]);
        const size_t o = ((size_t)(b * 1024 + m + e)) * 256 + n;
        if (LAST) {
          out[o] = v;
        } else {
          Xh[o] = f2bf(v);
        }
      }
    }
  }
}

extern "C" void kernel_launch(void* const* d_in, const int* in_sizes, int n_in,
                              void* d_out, int out_size, void* d_ws, size_t ws_size,
                              hipStream_t stream) {
  const float* x    = (const float*)d_in[0];
  const float* mask = (const float*)d_in[1];
  const float* adj  = (const float*)d_in[2];
  const float* W[3]  = {(const float*)d_in[3], (const float*)d_in[5], (const float*)d_in[7]};
  const float* bs[3] = {(const float*)d_in[4], (const float*)d_in[6], (const float*)d_in[8]};

  uint8_t* ws = (uint8_t*)d_ws;
  uint16_t* An  = (uint16_t*)(ws);                    // 67108864 B (tiled)
  uint16_t* Xh  = (uint16_t*)(ws + 67108864);         // 16777216
  uint16_t* Yth = (uint16_t*)(ws + 83886080);         // 16777216 (tiled)
  uint16_t* Wh  = (uint16_t*)(ws + 100663296);        // 393216
  uint16_t* Wl  = (uint16_t*)(ws + 101056512);        // 393216

  k_prep<<<dim3(41152), 256, 0, stream>>>(adj, An, x, Xh, W[0], W[1], W[2], Wh, Wl);

  for (int l = 0; l < 3; ++l) {
    k_linear<<<dim3(512, 2), 256, 0, stream>>>(Xh, Wh + l * 65536, Wl + l * 65536,
                                               bs[l], Yth);
    if (l < 2)
      k_agg<false><<<dim3(512), 256, 0, stream>>>(An, Yth, mask, Xh, nullptr);
    else
      k_agg<true><<<dim3(512), 256, 0, stream>>>(An, Yth, mask, nullptr,
                                                 (float*)d_out);
  }
}